// Round 2
// baseline (619.755 us; speedup 1.0000x reference)
//
#include <hip/hip_runtime.h>
#include <hip/hip_cooperative_groups.h>
#include <math.h>

namespace cg = cooperative_groups;

#define H   1024
#define V   50257
#define L   50
#define ENC 2048

// ws layout (floats). NO pre-zeroing needed: every cell is written before it
// is read within this launch (harness poison is harmless). WS_ES is zeroed in
// phase 6 (before kf's atomics). Total footprint ~7.2 MB (ws is ~800 MB per
// the 823-MB poison fill observed in rocprof).
#define WS_UP   0          // [16][1024]     u partials   (h  @ W_attn[0:1024])
#define WS_SP   16384      // [32][50][1024] S partials   (enc@ W_attn[1024:3072])
#define WS_GHP  1654784    // [16][3072]     gh partials  (h  @ whh)
#define WS_E    1703936    // [64]           attention scores e_l
#define WS_AA   1704000    // [2048]         attn_applied
#define WS_XRP  1706048    // [48][1024]     xr partials  (combine GEMV)
#define WS_GIP  1755200    // [16][3072]     gi partials  (x @ wih)
#define WS_ES   1804352    // [1]            exp-sum for log_softmax

// ---------------------------------------------------------------------------
// mid_coop: one cooperative kernel replacing memset+ka+k2+kc+kd+k5.
// 224 blocks x 256 thr (<=256 CUs -> co-residency guaranteed at any VGPR).
// 6 phases, 5 grid.sync(). Partial-sum buffers replace global atomics; the
// reduction over partials is folded into each consumer phase (L2/L3-resident).
// P1: u,S,gh partial GEMVs (224 block-units, same tiling as old ka)
// P2: e_l (50 blocks) + combine emb-rows partials (16 blocks)
// P3: softmax (redundant per block, 50 elems) + attn_applied (8 blocks)
// P4: combine aa-rows partials (32 blocks)
// P5: gi = relu(xr+cb) @ wih partials (48 blocks)
// P6: GRU gates -> h_new -> out[V..V+H) (4 blocks); block 4 zeroes WS_ES
// ---------------------------------------------------------------------------
__global__ __launch_bounds__(256) void mid_coop(
    const float* __restrict__ W,     const float* __restrict__ hid,
    const float* __restrict__ enc,   const float* __restrict__ whh,
    const float* __restrict__ combW, const float* __restrict__ emb,
    const long long* __restrict__ idx,
    const float* __restrict__ attn_b, const float* __restrict__ vW,
    const float* __restrict__ vb,    const float* __restrict__ comb_b,
    const float* __restrict__ wih,   const float* __restrict__ bih,
    const float* __restrict__ bhh,   float* __restrict__ ws,
    float* __restrict__ out)
{
    cg::grid_group grid = cg::this_grid();
    __shared__ float sm[10 * 64];
    const int tid = threadIdx.x;
    const int b = blockIdx.x;

    // ---------------- P1: u / S / gh partials (old ka, stores not atomics) --
    if (b < 16) {                      // u-part: rows [b*64, b*64+64)
        const float4* W4 = (const float4*)W;     // row stride 256 float4
        if (tid < 64) sm[tid] = hid[b * 64 + tid];
        __syncthreads();
        float4 acc = {0.f, 0.f, 0.f, 0.f};
        const int rowbase = b * 64;
        #pragma unroll 8
        for (int ii = 0; ii < 64; ++ii) {
            float4 w = W4[(rowbase + ii) * 256 + tid];
            float s = sm[ii];
            acc.x = fmaf(s, w.x, acc.x); acc.y = fmaf(s, w.y, acc.y);
            acc.z = fmaf(s, w.z, acc.z); acc.w = fmaf(s, w.w, acc.w);
        }
        ((float4*)(ws + WS_UP))[b * 256 + tid] = acc;
    } else if (b < 176) {              // S-part: 32 i-tiles x 5 l-tiles
        const float4* W4 = (const float4*)W;
        const int sb = b - 16;
        const int it = sb & 31;
        const int lt = sb >> 5;
        for (int t = tid; t < 10 * 64; t += 256)
            sm[t] = enc[(lt * 10 + (t >> 6)) * ENC + it * 64 + (t & 63)];
        __syncthreads();
        float4 acc[10];
        #pragma unroll
        for (int l = 0; l < 10; ++l) acc[l] = make_float4(0.f, 0.f, 0.f, 0.f);
        const int rowbase = 1024 + it * 64;
        #pragma unroll 4
        for (int ii = 0; ii < 64; ++ii) {
            float4 w = W4[(rowbase + ii) * 256 + tid];
            #pragma unroll
            for (int l = 0; l < 10; ++l) {
                float s = sm[l * 64 + ii];
                acc[l].x = fmaf(s, w.x, acc[l].x); acc[l].y = fmaf(s, w.y, acc[l].y);
                acc[l].z = fmaf(s, w.z, acc[l].z); acc[l].w = fmaf(s, w.w, acc[l].w);
            }
        }
        float4* SP4 = (float4*)(ws + WS_SP);
        #pragma unroll
        for (int l = 0; l < 10; ++l)
            SP4[(it * 50 + lt * 10 + l) * 256 + tid] = acc[l];
    } else {                           // gh-part: h @ whh
        const int gb = b - 176;
        const int it = gb & 15;
        const int jt = gb >> 4;
        const int rowbase = it * 64;
        if (tid < 64) sm[tid] = hid[rowbase + tid];
        __syncthreads();
        const float4* W4 = (const float4*)whh;   // row stride 768 float4
        float4 acc = {0.f, 0.f, 0.f, 0.f};
        const int col4 = jt * 256 + tid;
        #pragma unroll 8
        for (int ii = 0; ii < 64; ++ii) {
            float4 w = W4[(rowbase + ii) * 768 + col4];
            float s = sm[ii];
            acc.x = fmaf(s, w.x, acc.x); acc.y = fmaf(s, w.y, acc.y);
            acc.z = fmaf(s, w.z, acc.z); acc.w = fmaf(s, w.w, acc.w);
        }
        ((float4*)(ws + WS_GHP))[it * 768 + jt * 256 + tid] = acc;
    }
    grid.sync();

    // ---------------- P2: e_l (b<50) ; combine emb-rows partials (50<=b<66) -
    if (b < 50) {
        const float4* UP4 = (const float4*)(ws + WS_UP);
        const float4* SP4 = (const float4*)(ws + WS_SP);
        const float4* ab4 = (const float4*)attn_b;
        const float4* vW4 = (const float4*)vW;
        float4 u = {0.f, 0.f, 0.f, 0.f};
        #pragma unroll 4
        for (int it = 0; it < 16; ++it) {
            float4 t = UP4[it * 256 + tid];
            u.x += t.x; u.y += t.y; u.z += t.z; u.w += t.w;
        }
        #pragma unroll 4
        for (int it = 0; it < 32; ++it) {
            float4 t = SP4[(it * 50 + b) * 256 + tid];
            u.x += t.x; u.y += t.y; u.z += t.z; u.w += t.w;
        }
        float4 bb = ab4[tid];
        float4 vv = vW4[tid];
        float acc = fmaxf(u.x + bb.x, 0.f) * vv.x
                  + fmaxf(u.y + bb.y, 0.f) * vv.y
                  + fmaxf(u.z + bb.z, 0.f) * vv.z
                  + fmaxf(u.w + bb.w, 0.f) * vv.w;
        #pragma unroll
        for (int off = 32; off; off >>= 1) acc += __shfl_down(acc, off);
        if ((tid & 63) == 0) sm[tid >> 6] = acc;
        __syncthreads();
        if (tid == 0) ws[WS_E + b] = sm[0] + sm[1] + sm[2] + sm[3] + vb[0];
    } else if (b < 66) {
        const int unit = b - 50;           // combine rows [unit*64, +64) (emb)
        if (tid < 64) {
            const float* embrow = emb + (size_t)idx[0] * H;
            sm[tid] = embrow[unit * 64 + tid];
        }
        __syncthreads();
        const float4* W4 = (const float4*)combW;  // row stride 256 float4
        float4 acc = {0.f, 0.f, 0.f, 0.f};
        const int rowbase = unit * 64;
        #pragma unroll 8
        for (int ii = 0; ii < 64; ++ii) {
            float4 w = W4[(rowbase + ii) * 256 + tid];
            float s = sm[ii];
            acc.x = fmaf(s, w.x, acc.x); acc.y = fmaf(s, w.y, acc.y);
            acc.z = fmaf(s, w.z, acc.z); acc.w = fmaf(s, w.w, acc.w);
        }
        ((float4*)(ws + WS_XRP))[unit * 256 + tid] = acc;
    }
    grid.sync();

    // ---------------- P3: softmax (redundant) + attn_applied (b<8) ---------
    if (b < 8) {
        if (tid < 64) {
            float e = (tid < L) ? ws[WS_E + tid] : -1e30f;
            float m = e;
            #pragma unroll
            for (int off = 32; off; off >>= 1) m = fmaxf(m, __shfl_down(m, off));
            m = __shfl(m, 0);
            float ex = (tid < L) ? expf(e - m) : 0.f;
            float s = ex;
            #pragma unroll
            for (int off = 32; off; off >>= 1) s += __shfl_down(s, off);
            s = __shfl(s, 0);
            if (tid < L) {
                float w = ex / s;
                sm[tid] = w;
                if (b == 0) out[V + H + tid] = w;
            }
        }
        __syncthreads();
        const int col = b * 256 + tid;
        float a = 0.f;
        #pragma unroll 10
        for (int l = 0; l < L; ++l) a = fmaf(sm[l], enc[l * ENC + col], a);
        ws[WS_AA + col] = a;
    }
    grid.sync();

    // ---------------- P4: combine aa-rows partials (b<32) ------------------
    if (b < 32) {
        if (tid < 64) sm[tid] = ws[WS_AA + b * 64 + tid];
        __syncthreads();
        const float4* W4 = (const float4*)combW;
        float4 acc = {0.f, 0.f, 0.f, 0.f};
        const int rowbase = 1024 + b * 64;
        #pragma unroll 8
        for (int ii = 0; ii < 64; ++ii) {
            float4 w = W4[(rowbase + ii) * 256 + tid];
            float s = sm[ii];
            acc.x = fmaf(s, w.x, acc.x); acc.y = fmaf(s, w.y, acc.y);
            acc.z = fmaf(s, w.z, acc.z); acc.w = fmaf(s, w.w, acc.w);
        }
        ((float4*)(ws + WS_XRP))[(16 + b) * 256 + tid] = acc;
    }
    grid.sync();

    // ---------------- P5: gi partials = relu(xr+cb) @ wih (b<48) -----------
    if (b < 48) {
        const int it = b & 15, jt = b >> 4;
        if (tid < 64) {
            const int j = it * 64 + tid;
            float x = 0.f;
            #pragma unroll 8
            for (int p = 0; p < 48; ++p) x += ws[WS_XRP + p * 1024 + j];
            sm[tid] = fmaxf(x + comb_b[j], 0.f);
        }
        __syncthreads();
        const float4* W4 = (const float4*)wih;  // row stride 768 float4
        float4 acc = {0.f, 0.f, 0.f, 0.f};
        const int rowbase = it * 64;
        const int col4 = jt * 256 + tid;
        #pragma unroll 8
        for (int ii = 0; ii < 64; ++ii) {
            float4 w = W4[(rowbase + ii) * 768 + col4];
            float s = sm[ii];
            acc.x = fmaf(s, w.x, acc.x); acc.y = fmaf(s, w.y, acc.y);
            acc.z = fmaf(s, w.z, acc.z); acc.w = fmaf(s, w.w, acc.w);
        }
        ((float4*)(ws + WS_GIP))[it * 768 + jt * 256 + tid] = acc;
    }
    grid.sync();

    // ---------------- P6: GRU gates -> h_new (b<4); zero ES (b==4) ---------
    if (b < 4) {
        const int k = b * 256 + tid;
        float gi_r = 0.f, gi_z = 0.f, gi_n = 0.f;
        float gh_r = 0.f, gh_z = 0.f, gh_n = 0.f;
        #pragma unroll 4
        for (int it = 0; it < 16; ++it) {
            const float* gp = ws + WS_GIP + it * 3072;
            gi_r += gp[k]; gi_z += gp[H + k]; gi_n += gp[2 * H + k];
            const float* hp = ws + WS_GHP + it * 3072;
            gh_r += hp[k]; gh_z += hp[H + k]; gh_n += hp[2 * H + k];
        }
        float ir = gi_r + bih[k],       hr = gh_r + bhh[k];
        float iz = gi_z + bih[H + k],   hz = gh_z + bhh[H + k];
        float inn = gi_n + bih[2*H + k], hnn = gh_n + bhh[2*H + k];
        float r = 1.f / (1.f + expf(-(ir + hr)));
        float z = 1.f / (1.f + expf(-(iz + hz)));
        float n = tanhf(inn + r * hnn);
        out[V + k] = (1.f - z) * n + z * hid[k];
    } else if (b == 4 && tid == 0) {
        ws[WS_ES] = 0.f;
    }
}

// ---------------------------------------------------------------------------
// KF: logits (UNCHANGED from round-1 kernel except WS_ES offset).
// block = 512 thr (8 waves); block owns 64 vocab columns; wave w accumulates
// i-chunk [w*128, w*128+128); LDS reduce; wave 0 writes logit + exp-reduce.
// Row stride V=50257 floats is odd -> column-vector loads not naturally
// aligned; scalar dword loads are 256 B/wave contiguous (fully coalesced).
// ---------------------------------------------------------------------------
__global__ __launch_bounds__(512) void kf_logits(
    const float* __restrict__ outW, const float* __restrict__ outb,
    float* out, float* __restrict__ ws)
{
    __shared__ float hn[H];
    __shared__ float part[8 * 64];
    const int tid = threadIdx.x;
    for (int t = tid; t < H; t += 512) hn[t] = out[V + t];
    __syncthreads();

    const int wave = tid >> 6, lane = tid & 63;
    const int v = blockIdx.x * 64 + lane;
    float a0 = 0.f, a1 = 0.f, a2 = 0.f, a3 = 0.f;
    if (v < V) {
        const int ib = wave * 128;
        const float* p = outW + (size_t)ib * V + v;
        const size_t step = (size_t)V;
        #pragma unroll 4
        for (int i = 0; i < 128; i += 4) {
            float w0 = p[0], w1 = p[step], w2 = p[2 * step], w3 = p[3 * step];
            a0 = fmaf(hn[ib + i],     w0, a0);
            a1 = fmaf(hn[ib + i + 1], w1, a1);
            a2 = fmaf(hn[ib + i + 2], w2, a2);
            a3 = fmaf(hn[ib + i + 3], w3, a3);
            p += 4 * step;
        }
    }
    part[wave * 64 + lane] = (a0 + a1) + (a2 + a3);
    __syncthreads();

    if (wave == 0) {
        float s = 0.f;
        #pragma unroll
        for (int w = 0; w < 8; ++w) s += part[w * 64 + lane];
        float ex = 0.f;
        if (v < V) {
            float logit = s + outb[v];
            out[v] = logit;
            ex = expf(logit);
        }
        #pragma unroll
        for (int off = 32; off; off >>= 1) ex += __shfl_down(ex, off);
        if (lane == 0) atomicAdd(&ws[WS_ES], ex);
    }
}

// ---------------------------------------------------------------------------
// K7: out[v] = logit - log(sum exp)   (unchanged)
// ---------------------------------------------------------------------------
__global__ __launch_bounds__(256) void k7_finalize(
    float* out, const float* __restrict__ ws)
{
    const int v = blockIdx.x * 256 + threadIdx.x;
    const float lse = logf(ws[WS_ES]);
    if (v < V) out[v] -= lse;
}

extern "C" void kernel_launch(void* const* d_in, const int* in_sizes, int n_in,
                              void* d_out, int out_size, void* d_ws, size_t ws_size,
                              hipStream_t stream)
{
    const long long* idx = (const long long*)d_in[0];
    const float* hid = (const float*)d_in[1];
    const float* enc = (const float*)d_in[2];
    const float* emb = (const float*)d_in[3];
    const float* aW  = (const float*)d_in[4];
    const float* ab  = (const float*)d_in[5];
    const float* avW = (const float*)d_in[6];
    const float* avb = (const float*)d_in[7];
    const float* cW  = (const float*)d_in[8];
    const float* cb  = (const float*)d_in[9];
    const float* wih = (const float*)d_in[10];
    const float* bih = (const float*)d_in[11];
    const float* whh = (const float*)d_in[12];
    const float* bhh = (const float*)d_in[13];
    const float* oW  = (const float*)d_in[14];
    const float* ob  = (const float*)d_in[15];
    float* out = (float*)d_out;
    float* ws  = (float*)d_ws;

    void* args[] = { (void*)&aW, (void*)&hid, (void*)&enc, (void*)&whh,
                     (void*)&cW, (void*)&emb, (void*)&idx, (void*)&ab,
                     (void*)&avW, (void*)&avb, (void*)&cb, (void*)&wih,
                     (void*)&bih, (void*)&bhh, (void*)&ws, (void*)&out };
    hipLaunchCooperativeKernel((const void*)mid_coop, dim3(224), dim3(256),
                               args, 0, stream);
    kf_logits<<<786, 512, 0, stream>>>(oW, ob, out, ws);
    k7_finalize<<<197, 256, 0, stream>>>(out, ws);
}

// Round 3
// 503.935 us; speedup vs baseline: 1.2298x; 1.2298x over previous
//
#include <hip/hip_runtime.h>
#include <math.h>

#define H   1024
#define V   50257
#define L   50
#define ENC 2048

// ws layout in floats (accumulators zeroed by memset each launch)
#define WS_S   0        // 50*1024 attention pre-activations (enc @ W_e)
#define WS_U   51200    // 1024    h @ W_h
#define WS_XR  52224    // 1024    raw combine output (pre bias/relu)
#define WS_GI  53248    // 3072    x @ gru_wih
#define WS_GH  56320    // 3072    h @ gru_whh
#define WS_ES  59392    // 1       sum of exp(logits)
#define WS_AA  59520    // 2048    attn_applied (written, not accumulated)
#define WS_ZERO_BYTES (59520 * 4)

// ---------------------------------------------------------------------------
// KA: fused  u = h @ W[0:1024,:],  S = enc @ W[1024:3072,:],  gh = h @ whh
// grid 224 = 16 u-blocks (i-tile 64) + 160 S-blocks (32 i-tiles x 5 l-tiles
// of 10) + 48 gh-blocks (16 i-tiles x 3 j-tiles). fp32 atomics over i-tiles.
// NOTE (r2): do NOT replace this chain with a cooperative kernel —
// cg::grid.sync() measured ~33 us/sync on MI355X; launch boundaries win.
// ---------------------------------------------------------------------------
__global__ __launch_bounds__(256) void ka_fused(
    const float* __restrict__ W, const float* __restrict__ hid,
    const float* __restrict__ enc, const float* __restrict__ whh,
    float* __restrict__ ws)
{
    __shared__ float vec[10 * 64];
    const int tid = threadIdx.x;
    const int b = blockIdx.x;

    if (b < 16) {                      // u-part: rows [b*64, b*64+64)
        const float4* W4 = (const float4*)W;     // row stride 256 float4
        if (tid < 64) vec[tid] = hid[b * 64 + tid];
        __syncthreads();
        float4 acc = {0.f, 0.f, 0.f, 0.f};
        const int rowbase = b * 64;
        #pragma unroll 8
        for (int ii = 0; ii < 64; ++ii) {
            float4 w = W4[(rowbase + ii) * 256 + tid];
            float s = vec[ii];
            acc.x = fmaf(s, w.x, acc.x); acc.y = fmaf(s, w.y, acc.y);
            acc.z = fmaf(s, w.z, acc.z); acc.w = fmaf(s, w.w, acc.w);
        }
        float* u = ws + WS_U;
        int j0 = tid * 4;
        atomicAdd(&u[j0 + 0], acc.x); atomicAdd(&u[j0 + 1], acc.y);
        atomicAdd(&u[j0 + 2], acc.z); atomicAdd(&u[j0 + 3], acc.w);
    } else if (b < 176) {              // S-part
        const float4* W4 = (const float4*)W;
        const int sb = b - 16;
        const int it = sb & 31;        // 32 i-tiles of 64 over ENC
        const int lt = sb >> 5;        // 5 l-tiles of 10
        for (int t = tid; t < 10 * 64; t += 256)
            vec[t] = enc[(lt * 10 + (t >> 6)) * ENC + it * 64 + (t & 63)];
        __syncthreads();
        float4 acc[10];
        #pragma unroll
        for (int l = 0; l < 10; ++l) acc[l] = make_float4(0.f, 0.f, 0.f, 0.f);
        const int rowbase = 1024 + it * 64;
        #pragma unroll 4
        for (int ii = 0; ii < 64; ++ii) {
            float4 w = W4[(rowbase + ii) * 256 + tid];
            #pragma unroll
            for (int l = 0; l < 10; ++l) {
                float s = vec[l * 64 + ii];
                acc[l].x = fmaf(s, w.x, acc[l].x); acc[l].y = fmaf(s, w.y, acc[l].y);
                acc[l].z = fmaf(s, w.z, acc[l].z); acc[l].w = fmaf(s, w.w, acc[l].w);
            }
        }
        float* S = ws + WS_S;
        int j0 = tid * 4;
        #pragma unroll
        for (int l = 0; l < 10; ++l) {
            float* dst = S + (lt * 10 + l) * H + j0;
            atomicAdd(&dst[0], acc[l].x); atomicAdd(&dst[1], acc[l].y);
            atomicAdd(&dst[2], acc[l].z); atomicAdd(&dst[3], acc[l].w);
        }
    } else {                           // gh-part: h @ whh
        const int gb = b - 176;
        const int it = gb & 15;        // 16 i-tiles of 64 over H
        const int jt = gb >> 4;        // 3 j-tiles of 1024 cols
        const int rowbase = it * 64;
        if (tid < 64) vec[tid] = hid[rowbase + tid];
        __syncthreads();
        const float4* W4 = (const float4*)whh;   // row stride 768 float4
        float4 acc = {0.f, 0.f, 0.f, 0.f};
        const int col4 = jt * 256 + tid;
        #pragma unroll 8
        for (int ii = 0; ii < 64; ++ii) {
            float4 w = W4[(rowbase + ii) * 768 + col4];
            float s = vec[ii];
            acc.x = fmaf(s, w.x, acc.x); acc.y = fmaf(s, w.y, acc.y);
            acc.z = fmaf(s, w.z, acc.z); acc.w = fmaf(s, w.w, acc.w);
        }
        float* dst = ws + WS_GH;
        int j0 = jt * 1024 + tid * 4;
        atomicAdd(&dst[j0 + 0], acc.x); atomicAdd(&dst[j0 + 1], acc.y);
        atomicAdd(&dst[j0 + 2], acc.z); atomicAdd(&dst[j0 + 3], acc.w);
    }
}

// ---------------------------------------------------------------------------
// K2 (single block, 1024 thr): e_l = sum_j relu(u_j + S_lj + b_j)*v_j + vb,
// softmax over 50, attn_applied = w @ enc. Writes attn weights to out.
// ---------------------------------------------------------------------------
__global__ __launch_bounds__(1024) void k2_softmax_attn(
    const float* __restrict__ attn_b, const float* __restrict__ vW,
    const float* __restrict__ vb, const float* __restrict__ enc,
    float* __restrict__ ws, float* __restrict__ out)
{
    __shared__ float esm[64];
    __shared__ float wsm[64];
    const int tid = threadIdx.x;
    const int wave = tid >> 6, lane = tid & 63;
    const float* S = ws + WS_S;
    const float* u = ws + WS_U;

    for (int l = wave; l < L; l += 16) {
        float acc = 0.f;
        #pragma unroll 4
        for (int j = lane; j < H; j += 64) {
            float val = u[j] + S[l * H + j] + attn_b[j];
            acc += fmaxf(val, 0.f) * vW[j];
        }
        #pragma unroll
        for (int off = 32; off; off >>= 1) acc += __shfl_down(acc, off);
        if (lane == 0) esm[l] = acc + vb[0];
    }
    __syncthreads();

    if (wave == 0) {
        float e = (lane < L) ? esm[lane] : -1e30f;
        float m = e;
        #pragma unroll
        for (int off = 32; off; off >>= 1) m = fmaxf(m, __shfl_down(m, off));
        m = __shfl(m, 0);
        float ex = (lane < L) ? expf(e - m) : 0.f;
        float s = ex;
        #pragma unroll
        for (int off = 32; off; off >>= 1) s += __shfl_down(s, off);
        s = __shfl(s, 0);
        float w = ex / s;
        if (lane < L) { wsm[lane] = w; out[V + H + lane] = w; }
    }
    __syncthreads();

    // attn_applied via float2 over the full 2048-wide row
    float2* aa2 = (float2*)(ws + WS_AA);
    const float2* enc2 = (const float2*)enc;
    {
        float2 a = {0.f, 0.f};
        #pragma unroll 10
        for (int l = 0; l < L; ++l) {
            float2 e2 = enc2[l * (ENC / 2) + tid];
            float w = wsm[l];
            a.x = fmaf(w, e2.x, a.x); a.y = fmaf(w, e2.y, a.y);
        }
        aa2[tid] = a;
    }
}

// ---------------------------------------------------------------------------
// KC: xr = [emb_row, attn_applied] @ comb_W   (48 i-tile-64 blocks, atomics)
// ---------------------------------------------------------------------------
__global__ __launch_bounds__(256) void kc_combine(
    const float* __restrict__ combW, const float* __restrict__ emb,
    const int* __restrict__ idx, float* __restrict__ ws)
{
    __shared__ float vec[64];
    const int tid = threadIdx.x, b = blockIdx.x;
    const int rowbase = b * 64;
    if (tid < 64) {
        int i = rowbase + tid;
        const float* embrow = emb + (size_t)idx[0] * H;
        vec[tid] = (i < H) ? embrow[i] : ws[WS_AA + (i - H)];
    }
    __syncthreads();
    const float4* W4 = (const float4*)combW;  // row stride 256 float4
    float4 acc = {0.f, 0.f, 0.f, 0.f};
    #pragma unroll 8
    for (int ii = 0; ii < 64; ++ii) {
        float4 w = W4[(rowbase + ii) * 256 + tid];
        float s = vec[ii];
        acc.x = fmaf(s, w.x, acc.x); acc.y = fmaf(s, w.y, acc.y);
        acc.z = fmaf(s, w.z, acc.z); acc.w = fmaf(s, w.w, acc.w);
    }
    float* xr = ws + WS_XR;
    int j0 = tid * 4;
    atomicAdd(&xr[j0 + 0], acc.x); atomicAdd(&xr[j0 + 1], acc.y);
    atomicAdd(&xr[j0 + 2], acc.z); atomicAdd(&xr[j0 + 3], acc.w);
}

// ---------------------------------------------------------------------------
// KD: gi = relu(xr+comb_b) @ gru_wih   (48 blocks: 16 i-tiles x 3 j-tiles)
// ---------------------------------------------------------------------------
__global__ __launch_bounds__(256) void kd_gi(
    const float* __restrict__ wih, const float* __restrict__ comb_b,
    float* __restrict__ ws)
{
    __shared__ float vec[64];
    const int tid = threadIdx.x, b = blockIdx.x;
    const int it = b & 15, jt = b >> 4;
    const int rowbase = it * 64;
    if (tid < 64) {
        int i = rowbase + tid;
        vec[tid] = fmaxf(ws[WS_XR + i] + comb_b[i], 0.f);
    }
    __syncthreads();
    const float4* W4 = (const float4*)wih;  // row stride 768 float4
    float4 acc = {0.f, 0.f, 0.f, 0.f};
    const int col4 = jt * 256 + tid;
    #pragma unroll 8
    for (int ii = 0; ii < 64; ++ii) {
        float4 w = W4[(rowbase + ii) * 768 + col4];
        float s = vec[ii];
        acc.x = fmaf(s, w.x, acc.x); acc.y = fmaf(s, w.y, acc.y);
        acc.z = fmaf(s, w.z, acc.z); acc.w = fmaf(s, w.w, acc.w);
    }
    float* dst = ws + WS_GI;
    int j0 = jt * 1024 + tid * 4;
    atomicAdd(&dst[j0 + 0], acc.x); atomicAdd(&dst[j0 + 1], acc.y);
    atomicAdd(&dst[j0 + 2], acc.z); atomicAdd(&dst[j0 + 3], acc.w);
}

// ---------------------------------------------------------------------------
// K5: GRU gates -> h_new -> out[V .. V+H)
// ---------------------------------------------------------------------------
__global__ __launch_bounds__(256) void k5_gates(
    const float* __restrict__ ws, const float* __restrict__ bih,
    const float* __restrict__ bhh, const float* __restrict__ hid,
    float* __restrict__ out)
{
    const int k = blockIdx.x * 256 + threadIdx.x;
    float ir = ws[WS_GI + k]         + bih[k];
    float iz = ws[WS_GI + H + k]     + bih[H + k];
    float inn = ws[WS_GI + 2*H + k]  + bih[2*H + k];
    float hr = ws[WS_GH + k]         + bhh[k];
    float hz = ws[WS_GH + H + k]     + bhh[H + k];
    float hnn = ws[WS_GH + 2*H + k]  + bhh[2*H + k];
    float r = 1.f / (1.f + expf(-(ir + hr)));
    float z = 1.f / (1.f + expf(-(iz + hz)));
    float n = tanhf(inn + r * hnn);
    out[V + k] = (1.f - z) * n + z * hid[k];
}

// ---------------------------------------------------------------------------
// KF v2: logits, column-contiguous tiling for DRAM page locality.
// Block = 512 thr (8 waves) owns 256 CONSECUTIVE vocab columns; lane owns 4
// consecutive columns; wave w sweeps rows [w*128, w*128+128). Each per-row
// burst by a wave covers 1 KB contiguous (64 lanes x 4 adjacent dwords) vs
// the old 256-B window -> 4x better row-buffer locality, 197 blocks/row
// instead of 786. (float4 loads not legal: row stride V odd -> (r*V+c) mod 4
// varies with r.) LDS reduce 8 row-partials per column; waves 0-3 write
// logits + exp-reduce -> atomicAdd(expsum).
// ---------------------------------------------------------------------------
__global__ __launch_bounds__(512) void kf_logits(
    const float* __restrict__ outW, const float* __restrict__ outb,
    float* out, float* __restrict__ ws)
{
    __shared__ float hn[H];
    __shared__ float part[8 * 256];
    const int tid = threadIdx.x;
    for (int t = tid; t < H; t += 512) hn[t] = out[V + t];
    __syncthreads();

    const int wave = tid >> 6, lane = tid & 63;
    const int c0 = blockIdx.x * 256;
    const int cl = c0 + lane * 4;          // this lane's first column
    const int r0 = wave * 128;
    float a0 = 0.f, a1 = 0.f, a2 = 0.f, a3 = 0.f;
    const float* p = outW + (size_t)r0 * V + cl;
    if (cl + 3 < V) {                      // fast path: 4 in-bounds columns
        #pragma unroll 4
        for (int i = 0; i < 128; ++i) {
            float h = hn[r0 + i];
            a0 = fmaf(h, p[0], a0);
            a1 = fmaf(h, p[1], a1);
            a2 = fmaf(h, p[2], a2);
            a3 = fmaf(h, p[3], a3);
            p += V;
        }
    } else if (cl < V) {                   // tail block, guarded columns
        const bool b1 = (cl + 1 < V), b2 = (cl + 2 < V);
        for (int i = 0; i < 128; ++i) {
            float h = hn[r0 + i];
            a0 = fmaf(h, p[0], a0);
            if (b1) a1 = fmaf(h, p[1], a1);
            if (b2) a2 = fmaf(h, p[2], a2);
            p += V;
        }
    }
    float* pb = part + wave * 256 + lane * 4;
    pb[0] = a0; pb[1] = a1; pb[2] = a2; pb[3] = a3;
    __syncthreads();

    if (tid < 256) {
        const int v = c0 + tid;
        float s = 0.f;
        #pragma unroll
        for (int w = 0; w < 8; ++w) s += part[w * 256 + tid];
        float ex = 0.f;
        if (v < V) {
            float logit = s + outb[v];
            out[v] = logit;
            ex = expf(logit);
        }
        #pragma unroll
        for (int off = 32; off; off >>= 1) ex += __shfl_down(ex, off);
        if ((tid & 63) == 0) atomicAdd(&ws[WS_ES], ex);
    }
}

// ---------------------------------------------------------------------------
// K7: out[v] = logit - log(sum exp)
// ---------------------------------------------------------------------------
__global__ __launch_bounds__(256) void k7_finalize(
    float* out, const float* __restrict__ ws)
{
    const int v = blockIdx.x * 256 + threadIdx.x;
    const float lse = logf(ws[WS_ES]);
    if (v < V) out[v] -= lse;
}

extern "C" void kernel_launch(void* const* d_in, const int* in_sizes, int n_in,
                              void* d_out, int out_size, void* d_ws, size_t ws_size,
                              hipStream_t stream)
{
    const int*   idx = (const int*)d_in[0];
    const float* hid = (const float*)d_in[1];
    const float* enc = (const float*)d_in[2];
    const float* emb = (const float*)d_in[3];
    const float* aW  = (const float*)d_in[4];
    const float* ab  = (const float*)d_in[5];
    const float* avW = (const float*)d_in[6];
    const float* avb = (const float*)d_in[7];
    const float* cW  = (const float*)d_in[8];
    const float* cb  = (const float*)d_in[9];
    const float* wih = (const float*)d_in[10];
    const float* bih = (const float*)d_in[11];
    const float* whh = (const float*)d_in[12];
    const float* bhh = (const float*)d_in[13];
    const float* oW  = (const float*)d_in[14];
    const float* ob  = (const float*)d_in[15];
    float* out = (float*)d_out;
    float* ws  = (float*)d_ws;

    hipMemsetAsync(ws, 0, WS_ZERO_BYTES, stream);
    ka_fused<<<224, 256, 0, stream>>>(aW, hid, enc, whh, ws);
    k2_softmax_attn<<<1, 1024, 0, stream>>>(ab, avW, avb, enc, ws, out);
    kc_combine<<<48, 256, 0, stream>>>(cW, emb, idx, ws);
    kd_gi<<<48, 256, 0, stream>>>(wih, cb, ws);
    k5_gates<<<4, 256, 0, stream>>>(ws, bih, bhh, hid, out);
    kf_logits<<<197, 512, 0, stream>>>(oW, ob, out, ws);
    k7_finalize<<<197, 256, 0, stream>>>(out, ws);
}

// Round 4
// 473.780 us; speedup vs baseline: 1.3081x; 1.0636x over previous
//
#include <hip/hip_runtime.h>
#include <math.h>

#define H   1024
#define V   50257
#define L   50
#define ENC 2048

// ws layout (floats). NO zeroing needed: every cell is written before read
// within one launch sequence (harness poison harmless). WS_ES zeroed by k2a.
// All inter-kernel accumulation uses disjoint partial buffers + consumer-side
// reduction (patterns refcheck-verified inside round-2's mid_coop) -> zero
// device-scope atomics except kf's 197 ES adds.
#define WS_UP   0          // [16][1024]     u partials   (h  @ W_attn[0:1024])
#define WS_SP   16384      // [32][50][1024] S partials   (enc@ W_attn[1024:3072])
#define WS_GHP  1654784    // [16][3072]     gh partials  (h  @ whh)
#define WS_E    1703936    // [64]           attention scores e_l
#define WS_AA   1704000    // [2048]         attn_applied
#define WS_XRP  1706048    // [48][1024]     xr partials  (combine GEMV)
#define WS_GIP  1755200    // [16][3072]     gi partials  (x @ wih)
#define WS_ES   1804352    // [1]            exp-sum for log_softmax

// ---------------------------------------------------------------------------
// KA: u/S/gh partial GEMVs, plain stores (no atomics, no memset dependency).
// grid 224 = 16 u-blocks + 160 S-blocks (32 i-tiles x 5 l-tiles) + 48 gh.
// NOTE (r2): cg::grid.sync() costs ~33 us/sync on MI355X — never use it here.
// ---------------------------------------------------------------------------
__global__ __launch_bounds__(256) void ka_fused(
    const float* __restrict__ W, const float* __restrict__ hid,
    const float* __restrict__ enc, const float* __restrict__ whh,
    float* __restrict__ ws)
{
    __shared__ float vec[10 * 64];
    const int tid = threadIdx.x;
    const int b = blockIdx.x;

    if (b < 16) {                      // u-part: rows [b*64, b*64+64)
        const float4* W4 = (const float4*)W;     // row stride 256 float4
        if (tid < 64) vec[tid] = hid[b * 64 + tid];
        __syncthreads();
        float4 acc = {0.f, 0.f, 0.f, 0.f};
        const int rowbase = b * 64;
        #pragma unroll 8
        for (int ii = 0; ii < 64; ++ii) {
            float4 w = W4[(rowbase + ii) * 256 + tid];
            float s = vec[ii];
            acc.x = fmaf(s, w.x, acc.x); acc.y = fmaf(s, w.y, acc.y);
            acc.z = fmaf(s, w.z, acc.z); acc.w = fmaf(s, w.w, acc.w);
        }
        ((float4*)(ws + WS_UP))[b * 256 + tid] = acc;
    } else if (b < 176) {              // S-part: 32 i-tiles x 5 l-tiles
        const float4* W4 = (const float4*)W;
        const int sb = b - 16;
        const int it = sb & 31;
        const int lt = sb >> 5;
        for (int t = tid; t < 10 * 64; t += 256)
            vec[t] = enc[(lt * 10 + (t >> 6)) * ENC + it * 64 + (t & 63)];
        __syncthreads();
        float4 acc[10];
        #pragma unroll
        for (int l = 0; l < 10; ++l) acc[l] = make_float4(0.f, 0.f, 0.f, 0.f);
        const int rowbase = 1024 + it * 64;
        #pragma unroll 4
        for (int ii = 0; ii < 64; ++ii) {
            float4 w = W4[(rowbase + ii) * 256 + tid];
            #pragma unroll
            for (int l = 0; l < 10; ++l) {
                float s = vec[l * 64 + ii];
                acc[l].x = fmaf(s, w.x, acc[l].x); acc[l].y = fmaf(s, w.y, acc[l].y);
                acc[l].z = fmaf(s, w.z, acc[l].z); acc[l].w = fmaf(s, w.w, acc[l].w);
            }
        }
        float4* SP4 = (float4*)(ws + WS_SP);
        #pragma unroll
        for (int l = 0; l < 10; ++l)
            SP4[(it * 50 + lt * 10 + l) * 256 + tid] = acc[l];
    } else {                           // gh-part: h @ whh
        const int gb = b - 176;
        const int it = gb & 15;
        const int jt = gb >> 4;
        const int rowbase = it * 64;
        if (tid < 64) vec[tid] = hid[rowbase + tid];
        __syncthreads();
        const float4* W4 = (const float4*)whh;   // row stride 768 float4
        float4 acc = {0.f, 0.f, 0.f, 0.f};
        const int col4 = jt * 256 + tid;
        #pragma unroll 8
        for (int ii = 0; ii < 64; ++ii) {
            float4 w = W4[(rowbase + ii) * 768 + col4];
            float s = vec[ii];
            acc.x = fmaf(s, w.x, acc.x); acc.y = fmaf(s, w.y, acc.y);
            acc.z = fmaf(s, w.z, acc.z); acc.w = fmaf(s, w.w, acc.w);
        }
        ((float4*)(ws + WS_GHP))[it * 768 + jt * 256 + tid] = acc;
    }
}

// ---------------------------------------------------------------------------
// K2a: e_l = relu(sum of partials + b) . vW + vb, one block per l (50 blocks).
// Replaces the single-block serial score loop; also zeroes WS_ES.
// ---------------------------------------------------------------------------
__global__ __launch_bounds__(256) void k2a_scores(
    const float* __restrict__ attn_b, const float* __restrict__ vW,
    const float* __restrict__ vb, float* __restrict__ ws)
{
    __shared__ float red[4];
    const int tid = threadIdx.x;
    const int b = blockIdx.x;            // l index
    const float4* UP4 = (const float4*)(ws + WS_UP);
    const float4* SP4 = (const float4*)(ws + WS_SP);
    float4 u = {0.f, 0.f, 0.f, 0.f};
    #pragma unroll 4
    for (int it = 0; it < 16; ++it) {
        float4 t = UP4[it * 256 + tid];
        u.x += t.x; u.y += t.y; u.z += t.z; u.w += t.w;
    }
    #pragma unroll 4
    for (int it = 0; it < 32; ++it) {
        float4 t = SP4[(it * 50 + b) * 256 + tid];
        u.x += t.x; u.y += t.y; u.z += t.z; u.w += t.w;
    }
    float4 bb = ((const float4*)attn_b)[tid];
    float4 vv = ((const float4*)vW)[tid];
    float acc = fmaxf(u.x + bb.x, 0.f) * vv.x
              + fmaxf(u.y + bb.y, 0.f) * vv.y
              + fmaxf(u.z + bb.z, 0.f) * vv.z
              + fmaxf(u.w + bb.w, 0.f) * vv.w;
    #pragma unroll
    for (int off = 32; off; off >>= 1) acc += __shfl_down(acc, off);
    if ((tid & 63) == 0) red[tid >> 6] = acc;
    __syncthreads();
    if (tid == 0) {
        ws[WS_E + b] = red[0] + red[1] + red[2] + red[3] + vb[0];
        if (b == 0) ws[WS_ES] = 0.f;
    }
}

// ---------------------------------------------------------------------------
// K2b: softmax over 50 (redundant per block) + attn_applied (8 blocks x 256).
// Block 0 also writes attention weights to out[V+H ..).
// ---------------------------------------------------------------------------
__global__ __launch_bounds__(256) void k2b_softmax_aa(
    const float* __restrict__ enc, float* __restrict__ ws,
    float* __restrict__ out)
{
    __shared__ float sm[64];
    const int tid = threadIdx.x;
    const int b = blockIdx.x;
    if (tid < 64) {
        float e = (tid < L) ? ws[WS_E + tid] : -1e30f;
        float m = e;
        #pragma unroll
        for (int off = 32; off; off >>= 1) m = fmaxf(m, __shfl_down(m, off));
        m = __shfl(m, 0);
        float ex = (tid < L) ? expf(e - m) : 0.f;
        float s = ex;
        #pragma unroll
        for (int off = 32; off; off >>= 1) s += __shfl_down(s, off);
        s = __shfl(s, 0);
        if (tid < L) {
            float w = ex / s;
            sm[tid] = w;
            if (b == 0) out[V + H + tid] = w;
        }
    }
    __syncthreads();
    const int col = b * 256 + tid;
    float a = 0.f;
    #pragma unroll 10
    for (int l = 0; l < L; ++l) a = fmaf(sm[l], enc[l * ENC + col], a);
    ws[WS_AA + col] = a;
}

// ---------------------------------------------------------------------------
// KC: xr partials = [emb_row | attn_applied] @ comb_W. 48 blocks; block b
// covers input rows [b*64, b*64+64) (b<16 -> emb, b>=16 -> aa). Plain stores.
// ---------------------------------------------------------------------------
__global__ __launch_bounds__(256) void kc_combine(
    const float* __restrict__ combW, const float* __restrict__ emb,
    const int* __restrict__ idx, float* __restrict__ ws)
{
    __shared__ float vec[64];
    const int tid = threadIdx.x, b = blockIdx.x;
    const int rowbase = b * 64;
    if (tid < 64) {
        if (b < 16) {
            const float* embrow = emb + (size_t)idx[0] * H;
            vec[tid] = embrow[rowbase + tid];
        } else {
            vec[tid] = ws[WS_AA + (rowbase - H) + tid];
        }
    }
    __syncthreads();
    const float4* W4 = (const float4*)combW;  // row stride 256 float4
    float4 acc = {0.f, 0.f, 0.f, 0.f};
    #pragma unroll 8
    for (int ii = 0; ii < 64; ++ii) {
        float4 w = W4[(rowbase + ii) * 256 + tid];
        float s = vec[ii];
        acc.x = fmaf(s, w.x, acc.x); acc.y = fmaf(s, w.y, acc.y);
        acc.z = fmaf(s, w.z, acc.z); acc.w = fmaf(s, w.w, acc.w);
    }
    ((float4*)(ws + WS_XRP))[b * 256 + tid] = acc;
}

// ---------------------------------------------------------------------------
// KD: gi partials = relu(sum xr partials + cb) @ wih. 48 blocks (16 it x 3 jt).
// ---------------------------------------------------------------------------
__global__ __launch_bounds__(256) void kd_gi(
    const float* __restrict__ wih, const float* __restrict__ comb_b,
    float* __restrict__ ws)
{
    __shared__ float vec[64];
    const int tid = threadIdx.x, b = blockIdx.x;
    const int it = b & 15, jt = b >> 4;
    if (tid < 64) {
        const int j = it * 64 + tid;
        float x = 0.f;
        #pragma unroll 8
        for (int p = 0; p < 48; ++p) x += ws[WS_XRP + p * 1024 + j];
        vec[tid] = fmaxf(x + comb_b[j], 0.f);
    }
    __syncthreads();
    const float4* W4 = (const float4*)wih;  // row stride 768 float4
    float4 acc = {0.f, 0.f, 0.f, 0.f};
    const int rowbase = it * 64;
    const int col4 = jt * 256 + tid;
    #pragma unroll 8
    for (int ii = 0; ii < 64; ++ii) {
        float4 w = W4[(rowbase + ii) * 768 + col4];
        float s = vec[ii];
        acc.x = fmaf(s, w.x, acc.x); acc.y = fmaf(s, w.y, acc.y);
        acc.z = fmaf(s, w.z, acc.z); acc.w = fmaf(s, w.w, acc.w);
    }
    ((float4*)(ws + WS_GIP))[it * 768 + jt * 256 + tid] = acc;
}

// ---------------------------------------------------------------------------
// K5: reduce gi/gh partials -> GRU gates -> h_new -> out[V .. V+H)
// ---------------------------------------------------------------------------
__global__ __launch_bounds__(256) void k5_gates(
    const float* __restrict__ ws, const float* __restrict__ bih,
    const float* __restrict__ bhh, const float* __restrict__ hid,
    float* __restrict__ out)
{
    const int k = blockIdx.x * 256 + threadIdx.x;
    float gi_r = 0.f, gi_z = 0.f, gi_n = 0.f;
    float gh_r = 0.f, gh_z = 0.f, gh_n = 0.f;
    #pragma unroll 4
    for (int it = 0; it < 16; ++it) {
        const float* gp = ws + WS_GIP + it * 3072;
        gi_r += gp[k]; gi_z += gp[H + k]; gi_n += gp[2 * H + k];
        const float* hp = ws + WS_GHP + it * 3072;
        gh_r += hp[k]; gh_z += hp[H + k]; gh_n += hp[2 * H + k];
    }
    float ir  = gi_r + bih[k],         hr  = gh_r + bhh[k];
    float iz  = gi_z + bih[H + k],     hz  = gh_z + bhh[H + k];
    float inn = gi_n + bih[2 * H + k], hnn = gh_n + bhh[2 * H + k];
    float r = 1.f / (1.f + expf(-(ir + hr)));
    float z = 1.f / (1.f + expf(-(iz + hz)));
    float n = tanhf(inn + r * hnn);
    out[V + k] = (1.f - z) * n + z * hid[k];
}

// ---------------------------------------------------------------------------
// KF: logits, column-contiguous tiling (round-3 version, measured at the BW
// plateau; both 786x64col and 197x256col tilings identical). Block = 512 thr
// owns 256 consecutive vocab cols; lane owns 4 consecutive cols; wave w sweeps
// rows [w*128,+128). (float4 loads illegal: row stride V odd.)
// ---------------------------------------------------------------------------
__global__ __launch_bounds__(512) void kf_logits(
    const float* __restrict__ outW, const float* __restrict__ outb,
    float* out, float* __restrict__ ws)
{
    __shared__ float hn[H];
    __shared__ float part[8 * 256];
    const int tid = threadIdx.x;
    for (int t = tid; t < H; t += 512) hn[t] = out[V + t];
    __syncthreads();

    const int wave = tid >> 6, lane = tid & 63;
    const int c0 = blockIdx.x * 256;
    const int cl = c0 + lane * 4;
    const int r0 = wave * 128;
    float a0 = 0.f, a1 = 0.f, a2 = 0.f, a3 = 0.f;
    const float* p = outW + (size_t)r0 * V + cl;
    if (cl + 3 < V) {
        #pragma unroll 4
        for (int i = 0; i < 128; ++i) {
            float h = hn[r0 + i];
            a0 = fmaf(h, p[0], a0);
            a1 = fmaf(h, p[1], a1);
            a2 = fmaf(h, p[2], a2);
            a3 = fmaf(h, p[3], a3);
            p += V;
        }
    } else if (cl < V) {
        const bool b1 = (cl + 1 < V), b2 = (cl + 2 < V);
        for (int i = 0; i < 128; ++i) {
            float h = hn[r0 + i];
            a0 = fmaf(h, p[0], a0);
            if (b1) a1 = fmaf(h, p[1], a1);
            if (b2) a2 = fmaf(h, p[2], a2);
            p += V;
        }
    }
    float* pb = part + wave * 256 + lane * 4;
    pb[0] = a0; pb[1] = a1; pb[2] = a2; pb[3] = a3;
    __syncthreads();

    if (tid < 256) {
        const int v = c0 + tid;
        float s = 0.f;
        #pragma unroll
        for (int w = 0; w < 8; ++w) s += part[w * 256 + tid];
        float ex = 0.f;
        if (v < V) {
            float logit = s + outb[v];
            out[v] = logit;
            ex = expf(logit);
        }
        #pragma unroll
        for (int off = 32; off; off >>= 1) ex += __shfl_down(ex, off);
        if ((tid & 63) == 0) atomicAdd(&ws[WS_ES], ex);
    }
}

// ---------------------------------------------------------------------------
// K7: out[v] = logit - log(sum exp)
// ---------------------------------------------------------------------------
__global__ __launch_bounds__(256) void k7_finalize(
    float* out, const float* __restrict__ ws)
{
    const int v = blockIdx.x * 256 + threadIdx.x;
    const float lse = logf(ws[WS_ES]);
    if (v < V) out[v] -= lse;
}

extern "C" void kernel_launch(void* const* d_in, const int* in_sizes, int n_in,
                              void* d_out, int out_size, void* d_ws, size_t ws_size,
                              hipStream_t stream)
{
    const int*   idx = (const int*)d_in[0];
    const float* hid = (const float*)d_in[1];
    const float* enc = (const float*)d_in[2];
    const float* emb = (const float*)d_in[3];
    const float* aW  = (const float*)d_in[4];
    const float* ab  = (const float*)d_in[5];
    const float* avW = (const float*)d_in[6];
    const float* avb = (const float*)d_in[7];
    const float* cW  = (const float*)d_in[8];
    const float* cb  = (const float*)d_in[9];
    const float* wih = (const float*)d_in[10];
    const float* bih = (const float*)d_in[11];
    const float* whh = (const float*)d_in[12];
    const float* bhh = (const float*)d_in[13];
    const float* oW  = (const float*)d_in[14];
    const float* ob  = (const float*)d_in[15];
    float* out = (float*)d_out;
    float* ws  = (float*)d_ws;

    ka_fused<<<224, 256, 0, stream>>>(aW, hid, enc, whh, ws);
    k2a_scores<<<50, 256, 0, stream>>>(ab, avW, avb, ws);
    k2b_softmax_aa<<<8, 256, 0, stream>>>(enc, ws, out);
    kc_combine<<<48, 256, 0, stream>>>(cW, emb, idx, ws);
    kd_gi<<<48, 256, 0, stream>>>(wih, cb, ws);
    k5_gates<<<4, 256, 0, stream>>>(ws, bih, bhh, hid, out);
    kf_logits<<<197, 512, 0, stream>>>(oW, ob, out, ws);
    k7_finalize<<<197, 256, 0, stream>>>(out, ws);
}